// Round 2
// baseline (2028.757 us; speedup 1.0000x reference)
//
#include <hip/hip_runtime.h>
#include <hip/hip_bf16.h>

// RecurrentAgent: CNN (3 conv + fc) -> LSTM scan (T=128,B=16,H=256) -> heads.
// Design notes:
//  - All GEMM-shaped compute uses mfma_f32_16x16x32_bf16 (fp8 for LSTM W_hh).
//  - Activations between convs stored HWC so A-frags (8 consecutive k) are one
//    contiguous 16B load; conv3 K=3*3*64=576 needs no padding in (ky,kx,ci) order.
//  - /255 folded into conv1 weights (bias NOT folded).
//  - LSTM: single block, 8 waves, W_hh resident in VGPRs as fp8 e4m3 frags
//    (no per-step weight traffic, no inter-block sync). h in LDS fp8,
//    double-buffered, XOR-swizzled (row stride 256B would be 16-way conflict).
//    xg = feats@w_ih^T + b_ih + b_hh precomputed, stored bf16 in the exact
//    per-lane consumption order of the LSTM ([t][b][w2][q2][rr][g][r]).

#define DEV static __device__ __forceinline__

typedef __attribute__((ext_vector_type(4))) float f32x4;
typedef __attribute__((ext_vector_type(8))) short short8;
typedef __attribute__((ext_vector_type(4))) unsigned int u32x4;
typedef unsigned int uint32;
typedef unsigned short ushort16;
typedef unsigned long long u64;

DEV ushort16 f2bf(float f) {
  uint32 u = __builtin_bit_cast(uint32, f);
  return (ushort16)((u + 0x7FFFu + ((u >> 16) & 1u)) >> 16); // RNE
}
DEV float bf2f(ushort16 s) {
  uint32 u = ((uint32)s) << 16;
  return __builtin_bit_cast(float, u);
}
// float -> OCP e4m3 (RNE, saturate to 448). Dependency-free bit version.
DEV unsigned char f2e4m3(float f) {
  uint32 u = __builtin_bit_cast(uint32, f);
  uint32 s = (u >> 24) & 0x80u;
  uint32 a = u & 0x7FFFFFFFu;
  if (a >= 0x43E00000u) return (unsigned char)(s | 0x7Eu); // >=448 -> clamp
  int E = (int)(a >> 23) - 127;
  if (E >= -6) {
    uint32 mant = a & 0x7FFFFFu;
    uint32 keep = mant >> 20;
    uint32 rest = mant & 0xFFFFFu;
    keep += (rest > 0x80000u) || ((rest == 0x80000u) && (keep & 1u));
    uint32 Ee = (uint32)(E + 7);
    if (keep == 8u) { keep = 0u; Ee += 1u; }
    if (Ee >= 16u) return (unsigned char)(s | 0x7Eu);
    return (unsigned char)(s | (Ee << 3) | keep);
  } else {
    float af = __builtin_bit_cast(float, a);
    int q = (int)rintf(af * 512.f); // subnormal: units of 2^-9
    if (q > 8) q = 8;
    return (unsigned char)(s | (uint32)q);
  }
}
DEV float sigm(float x) { return 1.f / (1.f + __expf(-x)); }
DEV float tanh_(float x) {
  float a = fminf(fabsf(x), 15.f);
  float e = __expf(2.f * a);
  float r = (e - 1.f) / (e + 1.f);
  return copysignf(r, x);
}
DEV float relu_(float x) { return x > 0.f ? x : 0.f; }

// ---------------- weight prep: fp32 -> bf16 (+ layout permutes) ----------------
// w1b[32][256] = conv1_w/255 (k = ci*64+ky*8+kx, natural OIHW flatten)
// w2r[64][512]: k = ky*128+kx*32+ci   (HWC input order)
// w3r[64][576]: k = ky*192+kx*64+ci
// fcwb[512][3136], wihb[1024][512]: natural [N][K]
__global__ __launch_bounds__(256) void prep_k(
    const float* __restrict__ c1w, const float* __restrict__ c2w,
    const float* __restrict__ c3w, const float* __restrict__ fcw,
    const float* __restrict__ wih, ushort16* __restrict__ w1b,
    ushort16* __restrict__ w2r, ushort16* __restrict__ w3r,
    ushort16* __restrict__ fcwb, ushort16* __restrict__ wihb) {
  int i = blockIdx.x * 256 + threadIdx.x;
  if (i < 8192) w1b[i] = f2bf(c1w[i] * (1.f / 255.f));
  int j = i - 8192;
  if (j >= 0 && j < 32768) {
    int co = j >> 9, k = j & 511;
    int ky = k >> 7, kx = (k >> 5) & 3, ci = k & 31;
    w2r[j] = f2bf(c2w[((co * 32 + ci) << 4) + (ky << 2) + kx]);
  }
  int m = i - 40960;
  if (m >= 0 && m < 36864) {
    int co = m / 576, k = m - co * 576;
    int r3 = k >> 6, ci = k & 63;
    int ky = r3 / 3, kx = r3 - ky * 3;
    w3r[m] = f2bf(c3w[(co * 64 + ci) * 9 + ky * 3 + kx]);
  }
  int q = i - 77824;
  if (q >= 0 && q < 1605632) fcwb[q] = f2bf(fcw[q]);
  int z = i - 1683456;
  if (z >= 0 && z < 524288) wihb[z] = f2bf(wih[z]);
}

// ---------------- conv1: [2048,4,84,84] f32 -> out1 HWC [2048][400][32] bf16 ----------------
__global__ __launch_bounds__(256) void conv1_k(
    const float* __restrict__ img, const ushort16* __restrict__ w1b,
    const float* __restrict__ b1, ushort16* __restrict__ out1) {
  int wid = threadIdx.x >> 6, lane = threadIdx.x & 63;
  int l15 = lane & 15, rr = lane >> 4;
  int tile = blockIdx.x * 4 + wid; // 51200 tiles of 16 pixels
  int p = tile * 16 + l15;
  int n = p / 400, s = p - n * 400;
  int oy = s / 20, ox = s - oy * 20;
  const float* ib = img + (size_t)n * 4 * 7056;
  f32x4 ac0 = {0.f, 0.f, 0.f, 0.f}, ac1 = {0.f, 0.f, 0.f, 0.f};
#pragma unroll
  for (int kb = 0; kb < 8; ++kb) {
    int k0 = kb * 32 + rr * 8; // k = ci*64+ky*8+kx
    int ci = k0 >> 6, ky = (k0 >> 3) & 7;
    const float* ap = ib + ci * 7056 + (oy * 4 + ky) * 84 + ox * 4;
    f32x4 v0 = *(const f32x4*)ap;
    f32x4 v1 = *(const f32x4*)(ap + 4);
    short8 af;
    af[0] = (short)f2bf(v0[0]); af[1] = (short)f2bf(v0[1]);
    af[2] = (short)f2bf(v0[2]); af[3] = (short)f2bf(v0[3]);
    af[4] = (short)f2bf(v1[0]); af[5] = (short)f2bf(v1[1]);
    af[6] = (short)f2bf(v1[2]); af[7] = (short)f2bf(v1[3]);
    short8 bw0 = *(const short8*)(w1b + l15 * 256 + k0);
    short8 bw1 = *(const short8*)(w1b + (16 + l15) * 256 + k0);
    ac0 = __builtin_amdgcn_mfma_f32_16x16x32_bf16(af, bw0, ac0, 0, 0, 0);
    ac1 = __builtin_amdgcn_mfma_f32_16x16x32_bf16(af, bw1, ac1, 0, 0, 0);
  }
  float bia0 = b1[l15], bia1 = b1[16 + l15];
#pragma unroll
  for (int j = 0; j < 4; ++j) { // D row = rr*4+j, col(channel) = l15
    int pp = tile * 16 + rr * 4 + j;
    int nn = pp / 400, ss = pp - nn * 400;
    int ob = (nn * 400 + ss) * 32;
    out1[ob + l15] = f2bf(relu_(ac0[j] + bia0));
    out1[ob + 16 + l15] = f2bf(relu_(ac1[j] + bia1));
  }
}

// ---------------- conv2: out1 HWC -> out2 HWC [2048][81][64] bf16 ----------------
__global__ __launch_bounds__(256) void conv2_k(
    const ushort16* __restrict__ in1, const ushort16* __restrict__ w2r,
    const float* __restrict__ b2, ushort16* __restrict__ out2) {
  int wid = threadIdx.x >> 6, lane = threadIdx.x & 63;
  int l15 = lane & 15, rr = lane >> 4;
  int tile = blockIdx.x * 4 + wid; // 10368 tiles
  int p = tile * 16 + l15;
  int n = p / 81, s = p - n * 81;
  int oy = s / 9, ox = s - oy * 9;
  f32x4 ac[4];
#pragma unroll
  for (int t = 0; t < 4; ++t) ac[t] = (f32x4){0.f, 0.f, 0.f, 0.f};
#pragma unroll
  for (int kb = 0; kb < 16; ++kb) {
    int k0 = kb * 32 + rr * 8; // k = ky*128+kx*32+ci
    int ci0 = k0 & 31, kx = (k0 >> 5) & 3, ky = k0 >> 7;
    const ushort16* ap = in1 + ((n * 400 + (oy * 2 + ky) * 20 + (ox * 2 + kx)) * 32 + ci0);
    short8 af = *(const short8*)ap;
#pragma unroll
    for (int nt = 0; nt < 4; ++nt) {
      short8 bw = *(const short8*)(w2r + (nt * 16 + l15) * 512 + k0);
      ac[nt] = __builtin_amdgcn_mfma_f32_16x16x32_bf16(af, bw, ac[nt], 0, 0, 0);
    }
  }
#pragma unroll
  for (int nt = 0; nt < 4; ++nt) {
    float bia = b2[nt * 16 + l15];
#pragma unroll
    for (int j = 0; j < 4; ++j) {
      int pp = tile * 16 + rr * 4 + j;
      int nn = pp / 81, ss = pp - nn * 81;
      out2[(nn * 81 + ss) * 64 + nt * 16 + l15] = f2bf(relu_(ac[nt][j] + bia));
    }
  }
}

// ---------------- conv3: out2 HWC -> feats3 [2048][3136] bf16 (CHW flatten c*49+s) ----------------
__global__ __launch_bounds__(256) void conv3_k(
    const ushort16* __restrict__ in2, const ushort16* __restrict__ w3r,
    const float* __restrict__ b3, ushort16* __restrict__ f3) {
  __shared__ float tb[4][16][17]; // per-wave transpose tile (+1 pad)
  int wid = threadIdx.x >> 6, lane = threadIdx.x & 63;
  int l15 = lane & 15, rr = lane >> 4;
  int tile = blockIdx.x * 4 + wid; // 6272 tiles
  int p = tile * 16 + l15;
  int n = p / 49, s = p - n * 49;
  int oy = s / 7, ox = s - oy * 7;
  f32x4 ac[4];
#pragma unroll
  for (int t = 0; t < 4; ++t) ac[t] = (f32x4){0.f, 0.f, 0.f, 0.f};
#pragma unroll
  for (int kb = 0; kb < 18; ++kb) {
    int k0 = kb * 32 + rr * 8; // k = (ky*3+kx)*64 + ci
    int ci0 = k0 & 63, r3 = k0 >> 6;
    int ky = r3 / 3, kx = r3 - ky * 3;
    const ushort16* ap = in2 + ((n * 81 + (oy + ky) * 9 + (ox + kx)) * 64 + ci0);
    short8 af = *(const short8*)ap;
#pragma unroll
    for (int nt = 0; nt < 4; ++nt) {
      short8 bw = *(const short8*)(w3r + (nt * 16 + l15) * 576 + k0);
      ac[nt] = __builtin_amdgcn_mfma_f32_16x16x32_bf16(af, bw, ac[nt], 0, 0, 0);
    }
  }
  // store via wave-local LDS transpose so feats3 writes are contiguous along s
#pragma unroll
  for (int nt = 0; nt < 4; ++nt) {
    float bia = b3[nt * 16 + l15];
#pragma unroll
    for (int j = 0; j < 4; ++j) tb[wid][rr * 4 + j][l15] = relu_(ac[nt][j] + bia);
#pragma unroll
    for (int j2 = 0; j2 < 4; ++j2) {
      int ch = nt * 16 + rr * 4 + j2;
      float v = tb[wid][l15][rr * 4 + j2];
      int pp = tile * 16 + l15;
      int nn = pp / 49, ss = pp - nn * 49;
      f3[nn * 3136 + ch * 49 + ss] = f2bf(v);
    }
  }
}

// ---------------- fc: feats3 @ fcw^T + b, relu -> feats [2048][512] bf16 ----------------
__global__ __launch_bounds__(256) void fc_k(
    const ushort16* __restrict__ f3, const ushort16* __restrict__ fcwb,
    const float* __restrict__ fcb, ushort16* __restrict__ feats) {
  int wid = threadIdx.x >> 6, lane = threadIdx.x & 63;
  int l15 = lane & 15, rr = lane >> 4;
  int mt = blockIdx.x * 4 + wid; // 128 M-tiles
  int bn = blockIdx.y;           // 8 groups of 64 channels
  f32x4 ac[4];
#pragma unroll
  for (int t = 0; t < 4; ++t) ac[t] = (f32x4){0.f, 0.f, 0.f, 0.f};
  for (int kb = 0; kb < 98; ++kb) {
    int k0 = kb * 32 + rr * 8;
    short8 af = *(const short8*)(f3 + (mt * 16 + l15) * 3136 + k0);
#pragma unroll
    for (int nt = 0; nt < 4; ++nt) {
      short8 bw = *(const short8*)(fcwb + (bn * 64 + nt * 16 + l15) * 3136 + k0);
      ac[nt] = __builtin_amdgcn_mfma_f32_16x16x32_bf16(af, bw, ac[nt], 0, 0, 0);
    }
  }
#pragma unroll
  for (int nt = 0; nt < 4; ++nt) {
    int ch = bn * 64 + nt * 16 + l15;
    float bia = fcb[ch];
#pragma unroll
    for (int j = 0; j < 4; ++j) {
      int row = mt * 16 + rr * 4 + j;
      feats[row * 512 + ch] = f2bf(relu_(ac[nt][j] + bia));
    }
  }
}

// ---------------- xg: feats @ w_ih^T + b_ih + b_hh -> xgl bf16 in LSTM lane order ----------------
// element (t,b,gate): g=gate>>8, jf=gate&255, w2=jf>>5, q2=(jf>>4)&1, rr=(jf>>2)&3, r=jf&3
// idx = ((((t*16+b)*8 + w2)*2 + q2)*4 + rr)*16 + g*4 + r
__global__ __launch_bounds__(256) void xg_k(
    const ushort16* __restrict__ feats, const ushort16* __restrict__ wihb,
    const float* __restrict__ bih, const float* __restrict__ bhh,
    ushort16* __restrict__ xgl) {
  int wid = threadIdx.x >> 6, lane = threadIdx.x & 63;
  int l15 = lane & 15, rr = lane >> 4;
  int mt = blockIdx.x * 4 + wid; // 128 M-tiles
  int ng = blockIdx.y;           // 16 groups of 64 gates
  f32x4 ac[4];
#pragma unroll
  for (int t = 0; t < 4; ++t) ac[t] = (f32x4){0.f, 0.f, 0.f, 0.f};
#pragma unroll
  for (int kb = 0; kb < 16; ++kb) {
    int k0 = kb * 32 + rr * 8;
    short8 af = *(const short8*)(feats + (mt * 16 + l15) * 512 + k0);
#pragma unroll
    for (int nt = 0; nt < 4; ++nt) {
      short8 bw = *(const short8*)(wihb + (ng * 64 + nt * 16 + l15) * 512 + k0);
      ac[nt] = __builtin_amdgcn_mfma_f32_16x16x32_bf16(af, bw, ac[nt], 0, 0, 0);
    }
  }
#pragma unroll
  for (int nt = 0; nt < 4; ++nt) {
    int gate = ng * 64 + nt * 16 + l15;
    float bia = bih[gate] + bhh[gate];
    int g = gate >> 8, jf = gate & 255;
    int w2 = jf >> 5, q2 = (jf >> 4) & 1, rr2 = (jf >> 2) & 3, r = jf & 3;
#pragma unroll
    for (int j = 0; j < 4; ++j) {
      int row = mt * 16 + rr * 4 + j;
      int tt = row >> 4, bb = row & 15;
      int idx = ((((tt * 16 + bb) * 8 + w2) * 2 + q2) * 4 + rr2) * 16 + g * 4 + r;
      xgl[idx] = f2bf(ac[nt][j] + bia);
    }
  }
}

// ---------------- LSTM scan: 1 block, 8 waves, W_hh fp8 resident in VGPRs ----------------
// Wave w2 owns gate rows {g*256 + w2*32 + q2*16 + [0,16)} for g=0..3 (i,f,g,o), q2=0..1.
// Per lane: b = lane&15 (batch), rr = lane>>4. Lane's output j = w2*32+q2*16+rr*4+r.
__global__ __launch_bounds__(512, 2) void lstm_k(
    const float* __restrict__ whh, const ushort16* __restrict__ xgl,
    const int* __restrict__ done, const float* __restrict__ h0,
    const float* __restrict__ c0, float* __restrict__ hs,
    float* __restrict__ out) {
  __shared__ uint32 hbw[2][1024]; // h as fp8 [16][256], XOR-swizzled, double-buffered
  int tid = threadIdx.x;
  int w2 = tid >> 6, lane = tid & 63;
  int b = lane & 15, rr = lane >> 4;

  // --- preload W_hh as fp8 A-fragments: wf[g*2+q2][kb], fully register-resident ---
  u64 wf[8][8];
#pragma unroll
  for (int g = 0; g < 4; ++g)
#pragma unroll
    for (int q2 = 0; q2 < 2; ++q2) {
      int row = g * 256 + w2 * 32 + q2 * 16 + b; // A-row within tile = lane&15
#pragma unroll
      for (int kb = 0; kb < 8; ++kb) {
        const float* wp = whh + row * 256 + kb * 32 + rr * 8;
        f32x4 a0 = *(const f32x4*)wp;
        f32x4 a1 = *(const f32x4*)(wp + 4);
        u64 v = (u64)f2e4m3(a0[0]);
        v |= ((u64)f2e4m3(a0[1])) << 8;
        v |= ((u64)f2e4m3(a0[2])) << 16;
        v |= ((u64)f2e4m3(a0[3])) << 24;
        v |= ((u64)f2e4m3(a1[0])) << 32;
        v |= ((u64)f2e4m3(a1[1])) << 40;
        v |= ((u64)f2e4m3(a1[2])) << 48;
        v |= ((u64)f2e4m3(a1[3])) << 56;
        wf[g * 2 + q2][kb] = v;
      }
    }

  // --- c state (8 per lane) ---
  float c[8];
#pragma unroll
  for (int q2 = 0; q2 < 2; ++q2)
#pragma unroll
    for (int r = 0; r < 4; ++r)
      c[q2 * 4 + r] = c0[b * 256 + w2 * 32 + q2 * 16 + rr * 4 + r];

  // --- init h buffer 0 = h0 * (1-done[0]) quantized fp8 ---
  {
    int bb = tid >> 5, ck = tid & 31;
    float m0 = 1.f - (float)done[bb];
    u64 v = 0;
#pragma unroll
    for (int i = 0; i < 8; ++i) {
      float hv = h0[bb * 256 + ck * 8 + i] * m0;
      v |= ((u64)f2e4m3(hv)) << (8 * i);
    }
    ((u64*)&hbw[0][0])[((bb * 256 + ck * 8) ^ ((bb & 15) << 3)) >> 3] = v;
  }
  __syncthreads();

  union XU { u32x4 v; ushort16 s[8]; };
  XU xq[2][2];
#define PREF_XG(tt)                                                        \
  {                                                                        \
    int base_ = (((tt) * 16 + b) * 8 + w2) * 128 + rr * 16;                \
    xq[0][0].v = *(const u32x4*)(xgl + base_);                             \
    xq[0][1].v = *(const u32x4*)(xgl + base_ + 8);                         \
    xq[1][0].v = *(const u32x4*)(xgl + base_ + 64);                        \
    xq[1][1].v = *(const u32x4*)(xgl + base_ + 72);                        \
  }
  PREF_XG(0);

  for (int t = 0; t < 128; ++t) {
    int cur = t & 1, nxt = cur ^ 1;
    // B-fragments: h[b][k0..k0+8) fp8 from LDS (swizzled)
    u64 bq[8];
    const u64* hp = (const u64*)&hbw[cur][0];
#pragma unroll
    for (int kb = 0; kb < 8; ++kb)
      bq[kb] = hp[((b * 256 + kb * 32 + rr * 8) ^ ((b & 15) << 3)) >> 3];
    float mt = 1.f - (float)done[t * 16 + b];
    float mn = 0.f;
    if (t < 127) mn = 1.f - (float)done[(t + 1) * 16 + b];

#pragma unroll
    for (int q2 = 0; q2 < 2; ++q2) {
      f32x4 ac0 = {0.f, 0.f, 0.f, 0.f}, ac1 = ac0, ac2 = ac0, ac3 = ac0;
#pragma unroll
      for (int kb = 0; kb < 8; ++kb) {
        ac0 = __builtin_amdgcn_mfma_f32_16x16x32_fp8_fp8(
            (long long)wf[0 + q2][kb], (long long)bq[kb], ac0, 0, 0, 0);
        ac1 = __builtin_amdgcn_mfma_f32_16x16x32_fp8_fp8(
            (long long)wf[2 + q2][kb], (long long)bq[kb], ac1, 0, 0, 0);
        ac2 = __builtin_amdgcn_mfma_f32_16x16x32_fp8_fp8(
            (long long)wf[4 + q2][kb], (long long)bq[kb], ac2, 0, 0, 0);
        ac3 = __builtin_amdgcn_mfma_f32_16x16x32_fp8_fp8(
            (long long)wf[6 + q2][kb], (long long)bq[kb], ac3, 0, 0, 0);
      }
      int j0 = w2 * 32 + q2 * 16 + rr * 4;
      f32x4 hv4;
#pragma unroll
      for (int r = 0; r < 4; ++r) {
        float xi = bf2f(xq[q2][(0 + r) >> 3].s[(0 + r) & 7]);
        float xf = bf2f(xq[q2][(4 + r) >> 3].s[(4 + r) & 7]);
        float xgg = bf2f(xq[q2][(8 + r) >> 3].s[(8 + r) & 7]);
        float xo = bf2f(xq[q2][(12 + r) >> 3].s[(12 + r) & 7]);
        float ii = ac0[r] + xi, ff = ac1[r] + xf;
        float gg = ac2[r] + xgg, oo = ac3[r] + xo;
        float cold = c[q2 * 4 + r] * mt;
        float cn = sigm(ff) * cold + sigm(ii) * tanh_(gg);
        float hn = sigm(oo) * tanh_(cn);
        c[q2 * 4 + r] = cn;
        hv4[r] = hn;
      }
      *(f32x4*)(hs + (t * 16 + b) * 256 + j0) = hv4;
      if (t < 127) {
        uint32 pk = 0;
#pragma unroll
        for (int r = 0; r < 4; ++r)
          pk |= ((uint32)f2e4m3(hv4[r] * mn)) << (8 * r);
        hbw[nxt][((b * 256 + j0) ^ ((b & 15) << 3)) >> 2] = pk;
      } else {
        *(f32x4*)(out + 12288 + b * 256 + j0) = hv4; // hT
        f32x4 cc;
#pragma unroll
        for (int r = 0; r < 4; ++r) cc[r] = c[q2 * 4 + r];
        *(f32x4*)(out + 16384 + b * 256 + j0) = cc;  // cT
      }
    }
    if (t < 127) PREF_XG(t + 1);
    __syncthreads();
  }
}

// ---------------- heads: logits = hs@pol_w^T+pb ; v = hs@val_w^T+vb ----------------
__global__ __launch_bounds__(256) void heads_k(
    const float* __restrict__ hs, const float* __restrict__ pw,
    const float* __restrict__ pb, const float* __restrict__ vw,
    const float* __restrict__ vb, float* __restrict__ out) {
  __shared__ float wsm[1536];
  int tid = threadIdx.x;
  for (int i = tid; i < 1536; i += 256) wsm[i] = (i < 1280) ? pw[i] : vw[i - 1280];
  __syncthreads();
  int r = blockIdx.x * 256 + tid;
  const f32x4* hp = (const f32x4*)(hs + r * 256);
  float a[6] = {0.f, 0.f, 0.f, 0.f, 0.f, 0.f};
  for (int j = 0; j < 64; ++j) {
    f32x4 h = hp[j];
#pragma unroll
    for (int w = 0; w < 6; ++w) {
      f32x4 wv = *(const f32x4*)(wsm + w * 256 + j * 4);
      a[w] += h[0] * wv[0] + h[1] * wv[1] + h[2] * wv[2] + h[3] * wv[3];
    }
  }
#pragma unroll
  for (int w = 0; w < 5; ++w) out[r * 5 + w] = a[w] + pb[w];
  out[10240 + r] = a[5] + vb[0];
}

// ---------------- launch ----------------
extern "C" void kernel_launch(void* const* d_in, const int* in_sizes, int n_in,
                              void* d_out, int out_size, void* d_ws,
                              size_t ws_size, hipStream_t stream) {
  const float* img = (const float*)d_in[0];
  const int* done = (const int*)d_in[1];
  const float* h0 = (const float*)d_in[2];
  const float* c0 = (const float*)d_in[3];
  const float* c1w = (const float*)d_in[4];
  const float* c1b = (const float*)d_in[5];
  const float* c2w = (const float*)d_in[6];
  const float* c2b = (const float*)d_in[7];
  const float* c3w = (const float*)d_in[8];
  const float* c3b = (const float*)d_in[9];
  const float* fcw = (const float*)d_in[10];
  const float* fcb = (const float*)d_in[11];
  const float* wih = (const float*)d_in[12];
  const float* whh = (const float*)d_in[13];
  const float* bih = (const float*)d_in[14];
  const float* bhh = (const float*)d_in[15];
  const float* pw = (const float*)d_in[16];
  const float* pb = (const float*)d_in[17];
  const float* vw = (const float*)d_in[18];
  const float* vb = (const float*)d_in[19];
  float* out = (float*)d_out;
  char* ws = (char*)d_ws;

  // workspace layout (bytes, all 256-aligned); total ~94.7 MB
  ushort16* w1b = (ushort16*)(ws + 0);          //    16384
  ushort16* w2r = (ushort16*)(ws + 16384);      //    65536
  ushort16* w3r = (ushort16*)(ws + 81920);      //    73728
  ushort16* fcwb = (ushort16*)(ws + 155648);    //  3211264
  ushort16* wihb = (ushort16*)(ws + 3366912);   //  1048576
  ushort16* out1 = (ushort16*)(ws + 4415488);   // 52428800
  ushort16* out2 = (ushort16*)(ws + 56844288);  // 21233664
  ushort16* f3 = (ushort16*)(ws + 78077952);    // 12845056
  ushort16* feats = (ushort16*)(ws + 90923008); //  2097152
  ushort16* xgl = (ushort16*)(ws + 93020160);   //  4194304
  float* hs = (float*)(ws + 97214464);          //  2097152

  prep_k<<<8624, 256, 0, stream>>>(c1w, c2w, c3w, fcw, wih, w1b, w2r, w3r, fcwb, wihb);
  conv1_k<<<12800, 256, 0, stream>>>(img, w1b, c1b, out1);
  conv2_k<<<2592, 256, 0, stream>>>(out1, w2r, c2b, out2);
  conv3_k<<<1568, 256, 0, stream>>>(out2, w3r, c3b, f3);
  fc_k<<<dim3(32, 8), 256, 0, stream>>>(f3, fcwb, fcb, feats);
  xg_k<<<dim3(32, 16), 256, 0, stream>>>(feats, wihb, bih, bhh, xgl);
  lstm_k<<<1, 512, 0, stream>>>(whh, xgl, done, h0, c0, hs, out);
  heads_k<<<8, 256, 0, stream>>>(hs, pw, pb, vw, vb, out);
}

// Round 4
// 1540.526 us; speedup vs baseline: 1.3169x; 1.3169x over previous
//
#include <hip/hip_runtime.h>
#include <hip/hip_bf16.h>

// RecurrentAgent: CNN (3 conv + fc) -> LSTM scan (T=128,B=16,H=256) -> heads.
//  - CNN/fc/xg: mfma_f32_16x16x32_bf16, HWC activation layouts (unchanged,
//    verified round 2: absmax 0.0117).
//  - LSTM: single block, 8 waves. W_hh as fp8 e4m3 MFMA A-fragments in
//    *named scalar* u64 registers (round 2 showed VGPR_Count=60: the wf[8][8]
//    array was demoted to scratch -> 25x slowdown; named scalars force
//    register residency). h in LDS fp8, double-buffered, XOR-swizzled.

#define DEV static __device__ __forceinline__

typedef __attribute__((ext_vector_type(4))) float f32x4;
typedef __attribute__((ext_vector_type(8))) short short8;
typedef __attribute__((ext_vector_type(4))) unsigned int u32x4;
typedef unsigned int uint32;
typedef unsigned short ushort16;
typedef unsigned long long u64;

DEV ushort16 f2bf(float f) {
  uint32 u = __builtin_bit_cast(uint32, f);
  return (ushort16)((u + 0x7FFFu + ((u >> 16) & 1u)) >> 16); // RNE
}
DEV float bf2f(ushort16 s) {
  uint32 u = ((uint32)s) << 16;
  return __builtin_bit_cast(float, u);
}
DEV float bfh(uint32 w, int hi) { // bf16 from low/high half of a u32
  return __builtin_bit_cast(float, hi ? (w & 0xFFFF0000u) : (w << 16));
}
// float -> OCP e4m3 (RNE, saturate to 448).
DEV unsigned char f2e4m3(float f) {
  uint32 u = __builtin_bit_cast(uint32, f);
  uint32 s = (u >> 24) & 0x80u;
  uint32 a = u & 0x7FFFFFFFu;
  if (a >= 0x43E00000u) return (unsigned char)(s | 0x7Eu); // >=448 -> clamp
  int E = (int)(a >> 23) - 127;
  if (E >= -6) {
    uint32 mant = a & 0x7FFFFFu;
    uint32 keep = mant >> 20;
    uint32 rest = mant & 0xFFFFFu;
    keep += (rest > 0x80000u) || ((rest == 0x80000u) && (keep & 1u));
    uint32 Ee = (uint32)(E + 7);
    if (keep == 8u) { keep = 0u; Ee += 1u; }
    if (Ee >= 16u) return (unsigned char)(s | 0x7Eu);
    return (unsigned char)(s | (Ee << 3) | keep);
  } else {
    float af = __builtin_bit_cast(float, a);
    int q = (int)rintf(af * 512.f); // subnormal: units of 2^-9
    if (q > 8) q = 8;
    return (unsigned char)(s | (uint32)q);
  }
}
DEV float sigm(float x) { return 1.f / (1.f + __expf(-x)); }
DEV float tanh_(float x) {
  float a = fminf(fabsf(x), 15.f);
  float e = __expf(2.f * a);
  float r = (e - 1.f) / (e + 1.f);
  return copysignf(r, x);
}
DEV float relu_(float x) { return x > 0.f ? x : 0.f; }

// ---------------- weight prep: fp32 -> bf16 (+ layout permutes) ----------------
__global__ __launch_bounds__(256) void prep_k(
    const float* __restrict__ c1w, const float* __restrict__ c2w,
    const float* __restrict__ c3w, const float* __restrict__ fcw,
    const float* __restrict__ wih, ushort16* __restrict__ w1b,
    ushort16* __restrict__ w2r, ushort16* __restrict__ w3r,
    ushort16* __restrict__ fcwb, ushort16* __restrict__ wihb) {
  int i = blockIdx.x * 256 + threadIdx.x;
  if (i < 8192) w1b[i] = f2bf(c1w[i] * (1.f / 255.f));
  int j = i - 8192;
  if (j >= 0 && j < 32768) {
    int co = j >> 9, k = j & 511;
    int ky = k >> 7, kx = (k >> 5) & 3, ci = k & 31;
    w2r[j] = f2bf(c2w[((co * 32 + ci) << 4) + (ky << 2) + kx]);
  }
  int m = i - 40960;
  if (m >= 0 && m < 36864) {
    int co = m / 576, k = m - co * 576;
    int r3 = k >> 6, ci = k & 63;
    int ky = r3 / 3, kx = r3 - ky * 3;
    w3r[m] = f2bf(c3w[(co * 64 + ci) * 9 + ky * 3 + kx]);
  }
  int q = i - 77824;
  if (q >= 0 && q < 1605632) fcwb[q] = f2bf(fcw[q]);
  int z = i - 1683456;
  if (z >= 0 && z < 524288) wihb[z] = f2bf(wih[z]);
}

// ---------------- conv1: [2048,4,84,84] f32 -> out1 HWC [2048][400][32] bf16 ----------------
__global__ __launch_bounds__(256) void conv1_k(
    const float* __restrict__ img, const ushort16* __restrict__ w1b,
    const float* __restrict__ b1, ushort16* __restrict__ out1) {
  int wid = threadIdx.x >> 6, lane = threadIdx.x & 63;
  int l15 = lane & 15, rr = lane >> 4;
  int tile = blockIdx.x * 4 + wid; // 51200 tiles of 16 pixels
  int p = tile * 16 + l15;
  int n = p / 400, s = p - n * 400;
  int oy = s / 20, ox = s - oy * 20;
  const float* ib = img + (size_t)n * 4 * 7056;
  f32x4 ac0 = {0.f, 0.f, 0.f, 0.f}, ac1 = {0.f, 0.f, 0.f, 0.f};
#pragma unroll
  for (int kb = 0; kb < 8; ++kb) {
    int k0 = kb * 32 + rr * 8; // k = ci*64+ky*8+kx
    int ci = k0 >> 6, ky = (k0 >> 3) & 7;
    const float* ap = ib + ci * 7056 + (oy * 4 + ky) * 84 + ox * 4;
    f32x4 v0 = *(const f32x4*)ap;
    f32x4 v1 = *(const f32x4*)(ap + 4);
    short8 af;
    af[0] = (short)f2bf(v0[0]); af[1] = (short)f2bf(v0[1]);
    af[2] = (short)f2bf(v0[2]); af[3] = (short)f2bf(v0[3]);
    af[4] = (short)f2bf(v1[0]); af[5] = (short)f2bf(v1[1]);
    af[6] = (short)f2bf(v1[2]); af[7] = (short)f2bf(v1[3]);
    short8 bw0 = *(const short8*)(w1b + l15 * 256 + k0);
    short8 bw1 = *(const short8*)(w1b + (16 + l15) * 256 + k0);
    ac0 = __builtin_amdgcn_mfma_f32_16x16x32_bf16(af, bw0, ac0, 0, 0, 0);
    ac1 = __builtin_amdgcn_mfma_f32_16x16x32_bf16(af, bw1, ac1, 0, 0, 0);
  }
  float bia0 = b1[l15], bia1 = b1[16 + l15];
#pragma unroll
  for (int j = 0; j < 4; ++j) { // D row = rr*4+j, col(channel) = l15
    int pp = tile * 16 + rr * 4 + j;
    int nn = pp / 400, ss = pp - nn * 400;
    int ob = (nn * 400 + ss) * 32;
    out1[ob + l15] = f2bf(relu_(ac0[j] + bia0));
    out1[ob + 16 + l15] = f2bf(relu_(ac1[j] + bia1));
  }
}

// ---------------- conv2: out1 HWC -> out2 HWC [2048][81][64] bf16 ----------------
__global__ __launch_bounds__(256) void conv2_k(
    const ushort16* __restrict__ in1, const ushort16* __restrict__ w2r,
    const float* __restrict__ b2, ushort16* __restrict__ out2) {
  int wid = threadIdx.x >> 6, lane = threadIdx.x & 63;
  int l15 = lane & 15, rr = lane >> 4;
  int tile = blockIdx.x * 4 + wid; // 10368 tiles
  int p = tile * 16 + l15;
  int n = p / 81, s = p - n * 81;
  int oy = s / 9, ox = s - oy * 9;
  f32x4 ac[4];
#pragma unroll
  for (int t = 0; t < 4; ++t) ac[t] = (f32x4){0.f, 0.f, 0.f, 0.f};
#pragma unroll
  for (int kb = 0; kb < 16; ++kb) {
    int k0 = kb * 32 + rr * 8; // k = ky*128+kx*32+ci
    int ci0 = k0 & 31, kx = (k0 >> 5) & 3, ky = k0 >> 7;
    const ushort16* ap = in1 + ((n * 400 + (oy * 2 + ky) * 20 + (ox * 2 + kx)) * 32 + ci0);
    short8 af = *(const short8*)ap;
#pragma unroll
    for (int nt = 0; nt < 4; ++nt) {
      short8 bw = *(const short8*)(w2r + (nt * 16 + l15) * 512 + k0);
      ac[nt] = __builtin_amdgcn_mfma_f32_16x16x32_bf16(af, bw, ac[nt], 0, 0, 0);
    }
  }
#pragma unroll
  for (int nt = 0; nt < 4; ++nt) {
    float bia = b2[nt * 16 + l15];
#pragma unroll
    for (int j = 0; j < 4; ++j) {
      int pp = tile * 16 + rr * 4 + j;
      int nn = pp / 81, ss = pp - nn * 81;
      out2[(nn * 81 + ss) * 64 + nt * 16 + l15] = f2bf(relu_(ac[nt][j] + bia));
    }
  }
}

// ---------------- conv3: out2 HWC -> feats3 [2048][3136] bf16 (CHW flatten c*49+s) ----------------
__global__ __launch_bounds__(256) void conv3_k(
    const ushort16* __restrict__ in2, const ushort16* __restrict__ w3r,
    const float* __restrict__ b3, ushort16* __restrict__ f3) {
  __shared__ float tb[4][16][17]; // per-wave transpose tile (+1 pad)
  int wid = threadIdx.x >> 6, lane = threadIdx.x & 63;
  int l15 = lane & 15, rr = lane >> 4;
  int tile = blockIdx.x * 4 + wid; // 6272 tiles
  int p = tile * 16 + l15;
  int n = p / 49, s = p - n * 49;
  int oy = s / 7, ox = s - oy * 7;
  f32x4 ac[4];
#pragma unroll
  for (int t = 0; t < 4; ++t) ac[t] = (f32x4){0.f, 0.f, 0.f, 0.f};
#pragma unroll
  for (int kb = 0; kb < 18; ++kb) {
    int k0 = kb * 32 + rr * 8; // k = (ky*3+kx)*64 + ci
    int ci0 = k0 & 63, r3 = k0 >> 6;
    int ky = r3 / 3, kx = r3 - ky * 3;
    const ushort16* ap = in2 + ((n * 81 + (oy + ky) * 9 + (ox + kx)) * 64 + ci0);
    short8 af = *(const short8*)ap;
#pragma unroll
    for (int nt = 0; nt < 4; ++nt) {
      short8 bw = *(const short8*)(w3r + (nt * 16 + l15) * 576 + k0);
      ac[nt] = __builtin_amdgcn_mfma_f32_16x16x32_bf16(af, bw, ac[nt], 0, 0, 0);
    }
  }
#pragma unroll
  for (int nt = 0; nt < 4; ++nt) {
    float bia = b3[nt * 16 + l15];
#pragma unroll
    for (int j = 0; j < 4; ++j) tb[wid][rr * 4 + j][l15] = relu_(ac[nt][j] + bia);
#pragma unroll
    for (int j2 = 0; j2 < 4; ++j2) {
      int ch = nt * 16 + rr * 4 + j2;
      float v = tb[wid][l15][rr * 4 + j2];
      int pp = tile * 16 + l15;
      int nn = pp / 49, ss = pp - nn * 49;
      f3[nn * 3136 + ch * 49 + ss] = f2bf(v);
    }
  }
}

// ---------------- fc: feats3 @ fcw^T + b, relu -> feats [2048][512] bf16 ----------------
__global__ __launch_bounds__(256) void fc_k(
    const ushort16* __restrict__ f3, const ushort16* __restrict__ fcwb,
    const float* __restrict__ fcb, ushort16* __restrict__ feats) {
  int wid = threadIdx.x >> 6, lane = threadIdx.x & 63;
  int l15 = lane & 15, rr = lane >> 4;
  int mt = blockIdx.x * 4 + wid; // 128 M-tiles
  int bn = blockIdx.y;           // 8 groups of 64 channels
  f32x4 ac[4];
#pragma unroll
  for (int t = 0; t < 4; ++t) ac[t] = (f32x4){0.f, 0.f, 0.f, 0.f};
  for (int kb = 0; kb < 98; ++kb) {
    int k0 = kb * 32 + rr * 8;
    short8 af = *(const short8*)(f3 + (mt * 16 + l15) * 3136 + k0);
#pragma unroll
    for (int nt = 0; nt < 4; ++nt) {
      short8 bw = *(const short8*)(fcwb + (bn * 64 + nt * 16 + l15) * 3136 + k0);
      ac[nt] = __builtin_amdgcn_mfma_f32_16x16x32_bf16(af, bw, ac[nt], 0, 0, 0);
    }
  }
#pragma unroll
  for (int nt = 0; nt < 4; ++nt) {
    int ch = bn * 64 + nt * 16 + l15;
    float bia = fcb[ch];
#pragma unroll
    for (int j = 0; j < 4; ++j) {
      int row = mt * 16 + rr * 4 + j;
      feats[row * 512 + ch] = f2bf(relu_(ac[nt][j] + bia));
    }
  }
}

// ---------------- xg: feats @ w_ih^T + b_ih + b_hh -> xgl bf16 in LSTM lane order ----------------
// element (t,b,gate): g=gate>>8, jf=gate&255, w2=jf>>5, q2=(jf>>4)&1, rr=(jf>>2)&3, r=jf&3
// idx = ((((t*16+b)*8 + w2)*2 + q2)*4 + rr)*16 + g*4 + r
__global__ __launch_bounds__(256) void xg_k(
    const ushort16* __restrict__ feats, const ushort16* __restrict__ wihb,
    const float* __restrict__ bih, const float* __restrict__ bhh,
    ushort16* __restrict__ xgl) {
  int wid = threadIdx.x >> 6, lane = threadIdx.x & 63;
  int l15 = lane & 15, rr = lane >> 4;
  int mt = blockIdx.x * 4 + wid; // 128 M-tiles
  int ng = blockIdx.y;           // 16 groups of 64 gates
  f32x4 ac[4];
#pragma unroll
  for (int t = 0; t < 4; ++t) ac[t] = (f32x4){0.f, 0.f, 0.f, 0.f};
#pragma unroll
  for (int kb = 0; kb < 16; ++kb) {
    int k0 = kb * 32 + rr * 8;
    short8 af = *(const short8*)(feats + (mt * 16 + l15) * 512 + k0);
#pragma unroll
    for (int nt = 0; nt < 4; ++nt) {
      short8 bw = *(const short8*)(wihb + (ng * 64 + nt * 16 + l15) * 512 + k0);
      ac[nt] = __builtin_amdgcn_mfma_f32_16x16x32_bf16(af, bw, ac[nt], 0, 0, 0);
    }
  }
#pragma unroll
  for (int nt = 0; nt < 4; ++nt) {
    int gate = ng * 64 + nt * 16 + l15;
    float bia = bih[gate] + bhh[gate];
    int g = gate >> 8, jf = gate & 255;
    int w2 = jf >> 5, q2 = (jf >> 4) & 1, rr2 = (jf >> 2) & 3, r = jf & 3;
#pragma unroll
    for (int j = 0; j < 4; ++j) {
      int row = mt * 16 + rr * 4 + j;
      int tt = row >> 4, bb = row & 15;
      int idx = ((((tt * 16 + bb) * 8 + w2) * 2 + q2) * 4 + rr2) * 16 + g * 4 + r;
      xgl[idx] = f2bf(ac[nt][j] + bia);
    }
  }
}

// ---------------- LSTM scan: 1 block, 8 waves, W_hh fp8 in NAMED registers ----------------
DEV u64 pack8w(const float* p) {
  f32x4 a0 = *(const f32x4*)p;
  f32x4 a1 = *(const f32x4*)(p + 4);
  u64 v = (u64)f2e4m3(a0[0]);
  v |= ((u64)f2e4m3(a0[1])) << 8;
  v |= ((u64)f2e4m3(a0[2])) << 16;
  v |= ((u64)f2e4m3(a0[3])) << 24;
  v |= ((u64)f2e4m3(a1[0])) << 32;
  v |= ((u64)f2e4m3(a1[1])) << 40;
  v |= ((u64)f2e4m3(a1[2])) << 48;
  v |= ((u64)f2e4m3(a1[3])) << 56;
  return v;
}

#define MF(A, B, C) \
  __builtin_amdgcn_mfma_f32_16x16x32_fp8_fp8((long long)(A), (long long)(B), (C), 0, 0, 0)

#define KK8(WA, WB, WC, WD)                                                  \
  a_i = MF(WA##_0, bq0, a_i); a_f = MF(WB##_0, bq0, a_f);                    \
  a_g = MF(WC##_0, bq0, a_g); a_o = MF(WD##_0, bq0, a_o);                    \
  a_i = MF(WA##_1, bq1, a_i); a_f = MF(WB##_1, bq1, a_f);                    \
  a_g = MF(WC##_1, bq1, a_g); a_o = MF(WD##_1, bq1, a_o);                    \
  a_i = MF(WA##_2, bq2, a_i); a_f = MF(WB##_2, bq2, a_f);                    \
  a_g = MF(WC##_2, bq2, a_g); a_o = MF(WD##_2, bq2, a_o);                    \
  a_i = MF(WA##_3, bq3, a_i); a_f = MF(WB##_3, bq3, a_f);                    \
  a_g = MF(WC##_3, bq3, a_g); a_o = MF(WD##_3, bq3, a_o);                    \
  a_i = MF(WA##_4, bq4, a_i); a_f = MF(WB##_4, bq4, a_f);                    \
  a_g = MF(WC##_4, bq4, a_g); a_o = MF(WD##_4, bq4, a_o);                    \
  a_i = MF(WA##_5, bq5, a_i); a_f = MF(WB##_5, bq5, a_f);                    \
  a_g = MF(WC##_5, bq5, a_g); a_o = MF(WD##_5, bq5, a_o);                    \
  a_i = MF(WA##_6, bq6, a_i); a_f = MF(WB##_6, bq6, a_f);                    \
  a_g = MF(WC##_6, bq6, a_g); a_o = MF(WD##_6, bq6, a_o);                    \
  a_i = MF(WA##_7, bq7, a_i); a_f = MF(WB##_7, bq7, a_f);                    \
  a_g = MF(WC##_7, bq7, a_g); a_o = MF(WD##_7, bq7, a_o);

#define XG16(V0, V1, i)                                                      \
  bfh(((i) < 8 ? (uint32)(V0)[((i) >> 1) & 3] : (uint32)(V1)[((i) >> 1) & 3]), \
      ((i) & 1))

#define QSTEP(q2v, WA, WB, WC, WD, XV0, XV1, CV)                             \
  {                                                                          \
    f32x4 a_i = {0.f, 0.f, 0.f, 0.f}, a_f = a_i, a_g = a_i, a_o = a_i;       \
    KK8(WA, WB, WC, WD)                                                      \
    const int j0 = w2 * 32 + (q2v) * 16 + rr * 4;                            \
    f32x4 hv;                                                                \
    _Pragma("unroll") for (int r = 0; r < 4; ++r) {                          \
      float xi = XG16(XV0, XV1, 0 + r);                                      \
      float xf = XG16(XV0, XV1, 4 + r);                                      \
      float xg_ = XG16(XV0, XV1, 8 + r);                                     \
      float xo = XG16(XV0, XV1, 12 + r);                                     \
      float ii = a_i[r] + xi, ff = a_f[r] + xf;                              \
      float gg = a_g[r] + xg_, oo = a_o[r] + xo;                             \
      float cold = CV[r] * mtk;                                              \
      float cn = sigm(ff) * cold + sigm(ii) * tanh_(gg);                     \
      float hn = sigm(oo) * tanh_(cn);                                       \
      CV[r] = cn;                                                            \
      hv[r] = hn;                                                            \
    }                                                                        \
    *(f32x4*)(hs + (t * 16 + b) * 256 + j0) = hv;                            \
    if (t < 127) {                                                           \
      uint32 pk = 0;                                                         \
      _Pragma("unroll") for (int r = 0; r < 4; ++r)                          \
          pk |= ((uint32)f2e4m3(hv[r] * mnk)) << (8 * r);                    \
      hbw[nxt][((b * 256 + j0) ^ (b << 3)) >> 2] = pk;                       \
    } else {                                                                 \
      *(f32x4*)(out + 12288 + b * 256 + j0) = hv;                            \
      f32x4 cc;                                                              \
      _Pragma("unroll") for (int r = 0; r < 4; ++r) cc[r] = CV[r];           \
      *(f32x4*)(out + 16384 + b * 256 + j0) = cc;                            \
    }                                                                        \
  }

__global__ __launch_bounds__(512, 2) void lstm_k(
    const float* __restrict__ whh, const ushort16* __restrict__ xgl,
    const int* __restrict__ done, const float* __restrict__ h0,
    const float* __restrict__ c0, float* __restrict__ hs,
    float* __restrict__ out) {
  __shared__ uint32 hbw[2][1024]; // h as fp8 [16][256] bytes, XOR-swizzled, dbuf
  int tid = threadIdx.x;
  int w2 = tid >> 6, lane = tid & 63;
  int b = lane & 15, rr = lane >> 4;

  // W_hh fp8 A-fragments in named registers: wg<gq>_<kb>, gq = g*2+q2
#define WD8(gq)                                                              \
  u64 wg##gq##_0, wg##gq##_1, wg##gq##_2, wg##gq##_3, wg##gq##_4,            \
      wg##gq##_5, wg##gq##_6, wg##gq##_7
  WD8(0); WD8(1); WD8(2); WD8(3); WD8(4); WD8(5); WD8(6); WD8(7);
#define LW(gq, g_, q2_)                                                      \
  {                                                                          \
    const float* wp_ =                                                       \
        whh + ((g_) * 256 + w2 * 32 + (q2_) * 16 + b) * 256 + rr * 8;        \
    wg##gq##_0 = pack8w(wp_ + 0);                                            \
    wg##gq##_1 = pack8w(wp_ + 32);                                           \
    wg##gq##_2 = pack8w(wp_ + 64);                                           \
    wg##gq##_3 = pack8w(wp_ + 96);                                           \
    wg##gq##_4 = pack8w(wp_ + 128);                                          \
    wg##gq##_5 = pack8w(wp_ + 160);                                          \
    wg##gq##_6 = pack8w(wp_ + 192);                                          \
    wg##gq##_7 = pack8w(wp_ + 224);                                          \
  }
  LW(0, 0, 0); LW(1, 0, 1); LW(2, 1, 0); LW(3, 1, 1);
  LW(4, 2, 0); LW(5, 2, 1); LW(6, 3, 0); LW(7, 3, 1);

  // c state: 8 per lane in two named f32x4
  f32x4 cv0, cv1;
#pragma unroll
  for (int r = 0; r < 4; ++r) {
    cv0[r] = c0[b * 256 + w2 * 32 + 0 * 16 + rr * 4 + r];
    cv1[r] = c0[b * 256 + w2 * 32 + 1 * 16 + rr * 4 + r];
  }

  // init h buffer 0 = h0 * (1-done[0]) quantized fp8
  {
    int bb = tid >> 5, ck = tid & 31;
    float m0 = 1.f - (float)done[bb];
    u64 v = 0;
#pragma unroll
    for (int i = 0; i < 8; ++i) {
      float hv = h0[bb * 256 + ck * 8 + i] * m0;
      v |= ((u64)f2e4m3(hv)) << (8 * i);
    }
    ((u64*)&hbw[0][0])[((bb * 256 + ck * 8) ^ ((bb & 15) << 3)) >> 3] = v;
  }
  __syncthreads();

  u32x4 xv00, xv01, xv10, xv11;
#define PREF_XG(tt)                                                          \
  {                                                                          \
    const ushort16* xp_ = xgl + (((tt) * 16 + b) * 8 + w2) * 128 + rr * 16;  \
    xv00 = *(const u32x4*)(xp_);                                             \
    xv01 = *(const u32x4*)(xp_ + 8);                                         \
    xv10 = *(const u32x4*)(xp_ + 64);                                        \
    xv11 = *(const u32x4*)(xp_ + 72);                                        \
  }
  PREF_XG(0);

  u64 bq0, bq1, bq2, bq3, bq4, bq5, bq6, bq7;
#define LB(kb) bq##kb = hp[((b * 256 + (kb) * 32 + rr * 8) ^ (b << 3)) >> 3]

  for (int t = 0; t < 128; ++t) {
    int cur = t & 1, nxt = cur ^ 1;
    const u64* hp = (const u64*)&hbw[cur][0];
    LB(0); LB(1); LB(2); LB(3); LB(4); LB(5); LB(6); LB(7);
    float mtk = 1.f - (float)done[t * 16 + b];
    float mnk = (t < 127) ? (1.f - (float)done[(t + 1) * 16 + b]) : 0.f;

    QSTEP(0, wg0, wg2, wg4, wg6, xv00, xv01, cv0)
    QSTEP(1, wg1, wg3, wg5, wg7, xv10, xv11, cv1)

    if (t < 127) PREF_XG(t + 1);
    __syncthreads();
  }
}

// ---------------- heads: logits = hs@pol_w^T+pb ; v = hs@val_w^T+vb ----------------
__global__ __launch_bounds__(256) void heads_k(
    const float* __restrict__ hs, const float* __restrict__ pw,
    const float* __restrict__ pb, const float* __restrict__ vw,
    const float* __restrict__ vb, float* __restrict__ out) {
  __shared__ float wsm[1536];
  int tid = threadIdx.x;
  for (int i = tid; i < 1536; i += 256) wsm[i] = (i < 1280) ? pw[i] : vw[i - 1280];
  __syncthreads();
  int r = blockIdx.x * 256 + tid;
  const f32x4* hp = (const f32x4*)(hs + r * 256);
  float a[6] = {0.f, 0.f, 0.f, 0.f, 0.f, 0.f};
  for (int j = 0; j < 64; ++j) {
    f32x4 h = hp[j];
#pragma unroll
    for (int w = 0; w < 6; ++w) {
      f32x4 wv = *(const f32x4*)(wsm + w * 256 + j * 4);
      a[w] += h[0] * wv[0] + h[1] * wv[1] + h[2] * wv[2] + h[3] * wv[3];
    }
  }
#pragma unroll
  for (int w = 0; w < 5; ++w) out[r * 5 + w] = a[w] + pb[w];
  out[10240 + r] = a[5] + vb[0];
}

// ---------------- launch ----------------
extern "C" void kernel_launch(void* const* d_in, const int* in_sizes, int n_in,
                              void* d_out, int out_size, void* d_ws,
                              size_t ws_size, hipStream_t stream) {
  const float* img = (const float*)d_in[0];
  const int* done = (const int*)d_in[1];
  const float* h0 = (const float*)d_in[2];
  const float* c0 = (const float*)d_in[3];
  const float* c1w = (const float*)d_in[4];
  const float* c1b = (const float*)d_in[5];
  const float* c2w = (const float*)d_in[6];
  const float* c2b = (const float*)d_in[7];
  const float* c3w = (const float*)d_in[8];
  const float* c3b = (const float*)d_in[9];
  const float* fcw = (const float*)d_in[10];
  const float* fcb = (const float*)d_in[11];
  const float* wih = (const float*)d_in[12];
  const float* whh = (const float*)d_in[13];
  const float* bih = (const float*)d_in[14];
  const float* bhh = (const float*)d_in[15];
  const float* pw = (const float*)d_in[16];
  const float* pb = (const float*)d_in[17];
  const float* vw = (const float*)d_in[18];
  const float* vb = (const float*)d_in[19];
  float* out = (float*)d_out;
  char* ws = (char*)d_ws;

  ushort16* w1b = (ushort16*)(ws + 0);          //    16384
  ushort16* w2r = (ushort16*)(ws + 16384);      //    65536
  ushort16* w3r = (ushort16*)(ws + 81920);      //    73728
  ushort16* fcwb = (ushort16*)(ws + 155648);    //  3211264
  ushort16* wihb = (ushort16*)(ws + 3366912);   //  1048576
  ushort16* out1 = (ushort16*)(ws + 4415488);   // 52428800
  ushort16* out2 = (ushort16*)(ws + 56844288);  // 21233664
  ushort16* f3 = (ushort16*)(ws + 78077952);    // 12845056
  ushort16* feats = (ushort16*)(ws + 90923008); //  2097152
  ushort16* xgl = (ushort16*)(ws + 93020160);   //  4194304
  float* hs = (float*)(ws + 97214464);          //  2097152

  prep_k<<<8624, 256, 0, stream>>>(c1w, c2w, c3w, fcw, wih, w1b, w2r, w3r, fcwb, wihb);
  conv1_k<<<12800, 256, 0, stream>>>(img, w1b, c1b, out1);
  conv2_k<<<2592, 256, 0, stream>>>(out1, w2r, c2b, out2);
  conv3_k<<<1568, 256, 0, stream>>>(out2, w3r, c3b, f3);
  fc_k<<<dim3(32, 8), 256, 0, stream>>>(f3, fcwb, fcb, feats);
  xg_k<<<dim3(32, 16), 256, 0, stream>>>(feats, wihb, bih, bhh, xgl);
  lstm_k<<<1, 512, 0, stream>>>(whh, xgl, done, h0, c0, hs, out);
  heads_k<<<8, 256, 0, stream>>>(hs, pw, pb, vw, vb, out);
}

// Round 5
// 1033.375 us; speedup vs baseline: 1.9632x; 1.4908x over previous
//
#include <hip/hip_runtime.h>
#include <hip/hip_bf16.h>

// RecurrentAgent: CNN (3 conv + fc) -> LSTM scan (T=128,B=16,H=256) -> heads.
//  - CNN/fc/xg: mfma_f32_16x16x32_bf16, HWC activation layouts (unchanged,
//    verified round 2/4: absmax 0.0117).
//  - LSTM: single block, 8 waves. W_hh as fp8 e4m3 MFMA A-fragments in named
//    scalar u64 registers. h in LDS fp8, double-buffered, XOR-swizzled.
//    Round-4 postmortem: epilogue was VALU-bound (div sequences + branchy
//    sw fp8 cvt) and xg prefetch latency was barrier-exposed. This round:
//    v_exp/v_rcp gates, hw v_cvt_pk_fp8_f32 packs, ping-pong xg prefetch.

#define DEV static __device__ __forceinline__

typedef __attribute__((ext_vector_type(4))) float f32x4;
typedef __attribute__((ext_vector_type(8))) short short8;
typedef __attribute__((ext_vector_type(4))) unsigned int u32x4;
typedef unsigned int uint32;
typedef unsigned short ushort16;
typedef unsigned long long u64;

DEV ushort16 f2bf(float f) {
  uint32 u = __builtin_bit_cast(uint32, f);
  return (ushort16)((u + 0x7FFFu + ((u >> 16) & 1u)) >> 16); // RNE
}
DEV float bf2f(ushort16 s) {
  uint32 u = ((uint32)s) << 16;
  return __builtin_bit_cast(float, u);
}
DEV float bfh(uint32 w, int hi) { // bf16 from low/high half of a u32
  return __builtin_bit_cast(float, hi ? (w & 0xFFFF0000u) : (w << 16));
}
// 4 floats -> 4 OCP e4m3 bytes via hardware cvt (RNE, saturating)
DEV uint32 pk4_fp8(float a, float b, float c, float d) {
  uint32 v = __builtin_amdgcn_cvt_pk_fp8_f32(a, b, 0u, false); // bytes 0,1
  v = __builtin_amdgcn_cvt_pk_fp8_f32(c, d, v, true);          // bytes 2,3
  return v;
}
DEV float sigm(float x) { return __builtin_amdgcn_rcpf(1.f + __expf(-x)); }
DEV float tanh_(float x) {
  float a = fminf(fabsf(x), 15.f);
  float e = __expf(2.f * a);
  float r = 1.f - 2.f * __builtin_amdgcn_rcpf(e + 1.f);
  return copysignf(r, x);
}
DEV float relu_(float x) { return x > 0.f ? x : 0.f; }

// ---------------- weight prep: fp32 -> bf16 (+ layout permutes) ----------------
__global__ __launch_bounds__(256) void prep_k(
    const float* __restrict__ c1w, const float* __restrict__ c2w,
    const float* __restrict__ c3w, const float* __restrict__ fcw,
    const float* __restrict__ wih, ushort16* __restrict__ w1b,
    ushort16* __restrict__ w2r, ushort16* __restrict__ w3r,
    ushort16* __restrict__ fcwb, ushort16* __restrict__ wihb) {
  int i = blockIdx.x * 256 + threadIdx.x;
  if (i < 8192) w1b[i] = f2bf(c1w[i] * (1.f / 255.f));
  int j = i - 8192;
  if (j >= 0 && j < 32768) {
    int co = j >> 9, k = j & 511;
    int ky = k >> 7, kx = (k >> 5) & 3, ci = k & 31;
    w2r[j] = f2bf(c2w[((co * 32 + ci) << 4) + (ky << 2) + kx]);
  }
  int m = i - 40960;
  if (m >= 0 && m < 36864) {
    int co = m / 576, k = m - co * 576;
    int r3 = k >> 6, ci = k & 63;
    int ky = r3 / 3, kx = r3 - ky * 3;
    w3r[m] = f2bf(c3w[(co * 64 + ci) * 9 + ky * 3 + kx]);
  }
  int q = i - 77824;
  if (q >= 0 && q < 1605632) fcwb[q] = f2bf(fcw[q]);
  int z = i - 1683456;
  if (z >= 0 && z < 524288) wihb[z] = f2bf(wih[z]);
}

// ---------------- conv1: [2048,4,84,84] f32 -> out1 HWC [2048][400][32] bf16 ----------------
__global__ __launch_bounds__(256) void conv1_k(
    const float* __restrict__ img, const ushort16* __restrict__ w1b,
    const float* __restrict__ b1, ushort16* __restrict__ out1) {
  int wid = threadIdx.x >> 6, lane = threadIdx.x & 63;
  int l15 = lane & 15, rr = lane >> 4;
  int tile = blockIdx.x * 4 + wid; // 51200 tiles of 16 pixels
  int p = tile * 16 + l15;
  int n = p / 400, s = p - n * 400;
  int oy = s / 20, ox = s - oy * 20;
  const float* ib = img + (size_t)n * 4 * 7056;
  f32x4 ac0 = {0.f, 0.f, 0.f, 0.f}, ac1 = {0.f, 0.f, 0.f, 0.f};
#pragma unroll
  for (int kb = 0; kb < 8; ++kb) {
    int k0 = kb * 32 + rr * 8; // k = ci*64+ky*8+kx
    int ci = k0 >> 6, ky = (k0 >> 3) & 7;
    const float* ap = ib + ci * 7056 + (oy * 4 + ky) * 84 + ox * 4;
    f32x4 v0 = *(const f32x4*)ap;
    f32x4 v1 = *(const f32x4*)(ap + 4);
    short8 af;
    af[0] = (short)f2bf(v0[0]); af[1] = (short)f2bf(v0[1]);
    af[2] = (short)f2bf(v0[2]); af[3] = (short)f2bf(v0[3]);
    af[4] = (short)f2bf(v1[0]); af[5] = (short)f2bf(v1[1]);
    af[6] = (short)f2bf(v1[2]); af[7] = (short)f2bf(v1[3]);
    short8 bw0 = *(const short8*)(w1b + l15 * 256 + k0);
    short8 bw1 = *(const short8*)(w1b + (16 + l15) * 256 + k0);
    ac0 = __builtin_amdgcn_mfma_f32_16x16x32_bf16(af, bw0, ac0, 0, 0, 0);
    ac1 = __builtin_amdgcn_mfma_f32_16x16x32_bf16(af, bw1, ac1, 0, 0, 0);
  }
  float bia0 = b1[l15], bia1 = b1[16 + l15];
#pragma unroll
  for (int j = 0; j < 4; ++j) { // D row = rr*4+j, col(channel) = l15
    int pp = tile * 16 + rr * 4 + j;
    int nn = pp / 400, ss = pp - nn * 400;
    int ob = (nn * 400 + ss) * 32;
    out1[ob + l15] = f2bf(relu_(ac0[j] + bia0));
    out1[ob + 16 + l15] = f2bf(relu_(ac1[j] + bia1));
  }
}

// ---------------- conv2: out1 HWC -> out2 HWC [2048][81][64] bf16 ----------------
__global__ __launch_bounds__(256) void conv2_k(
    const ushort16* __restrict__ in1, const ushort16* __restrict__ w2r,
    const float* __restrict__ b2, ushort16* __restrict__ out2) {
  int wid = threadIdx.x >> 6, lane = threadIdx.x & 63;
  int l15 = lane & 15, rr = lane >> 4;
  int tile = blockIdx.x * 4 + wid; // 10368 tiles
  int p = tile * 16 + l15;
  int n = p / 81, s = p - n * 81;
  int oy = s / 9, ox = s - oy * 9;
  f32x4 ac[4];
#pragma unroll
  for (int t = 0; t < 4; ++t) ac[t] = (f32x4){0.f, 0.f, 0.f, 0.f};
#pragma unroll
  for (int kb = 0; kb < 16; ++kb) {
    int k0 = kb * 32 + rr * 8; // k = ky*128+kx*32+ci
    int ci0 = k0 & 31, kx = (k0 >> 5) & 3, ky = k0 >> 7;
    const ushort16* ap = in1 + ((n * 400 + (oy * 2 + ky) * 20 + (ox * 2 + kx)) * 32 + ci0);
    short8 af = *(const short8*)ap;
#pragma unroll
    for (int nt = 0; nt < 4; ++nt) {
      short8 bw = *(const short8*)(w2r + (nt * 16 + l15) * 512 + k0);
      ac[nt] = __builtin_amdgcn_mfma_f32_16x16x32_bf16(af, bw, ac[nt], 0, 0, 0);
    }
  }
#pragma unroll
  for (int nt = 0; nt < 4; ++nt) {
    float bia = b2[nt * 16 + l15];
#pragma unroll
    for (int j = 0; j < 4; ++j) {
      int pp = tile * 16 + rr * 4 + j;
      int nn = pp / 81, ss = pp - nn * 81;
      out2[(nn * 81 + ss) * 64 + nt * 16 + l15] = f2bf(relu_(ac[nt][j] + bia));
    }
  }
}

// ---------------- conv3: out2 HWC -> feats3 [2048][3136] bf16 (CHW flatten c*49+s) ----------------
__global__ __launch_bounds__(256) void conv3_k(
    const ushort16* __restrict__ in2, const ushort16* __restrict__ w3r,
    const float* __restrict__ b3, ushort16* __restrict__ f3) {
  __shared__ float tb[4][16][17]; // per-wave transpose tile (+1 pad)
  int wid = threadIdx.x >> 6, lane = threadIdx.x & 63;
  int l15 = lane & 15, rr = lane >> 4;
  int tile = blockIdx.x * 4 + wid; // 6272 tiles
  int p = tile * 16 + l15;
  int n = p / 49, s = p - n * 49;
  int oy = s / 7, ox = s - oy * 7;
  f32x4 ac[4];
#pragma unroll
  for (int t = 0; t < 4; ++t) ac[t] = (f32x4){0.f, 0.f, 0.f, 0.f};
#pragma unroll
  for (int kb = 0; kb < 18; ++kb) {
    int k0 = kb * 32 + rr * 8; // k = (ky*3+kx)*64 + ci
    int ci0 = k0 & 63, r3 = k0 >> 6;
    int ky = r3 / 3, kx = r3 - ky * 3;
    const ushort16* ap = in2 + ((n * 81 + (oy + ky) * 9 + (ox + kx)) * 64 + ci0);
    short8 af = *(const short8*)ap;
#pragma unroll
    for (int nt = 0; nt < 4; ++nt) {
      short8 bw = *(const short8*)(w3r + (nt * 16 + l15) * 576 + k0);
      ac[nt] = __builtin_amdgcn_mfma_f32_16x16x32_bf16(af, bw, ac[nt], 0, 0, 0);
    }
  }
#pragma unroll
  for (int nt = 0; nt < 4; ++nt) {
    float bia = b3[nt * 16 + l15];
#pragma unroll
    for (int j = 0; j < 4; ++j) tb[wid][rr * 4 + j][l15] = relu_(ac[nt][j] + bia);
#pragma unroll
    for (int j2 = 0; j2 < 4; ++j2) {
      int ch = nt * 16 + rr * 4 + j2;
      float v = tb[wid][l15][rr * 4 + j2];
      int pp = tile * 16 + l15;
      int nn = pp / 49, ss = pp - nn * 49;
      f3[nn * 3136 + ch * 49 + ss] = f2bf(v);
    }
  }
}

// ---------------- fc: feats3 @ fcw^T + b, relu -> feats [2048][512] bf16 ----------------
__global__ __launch_bounds__(256) void fc_k(
    const ushort16* __restrict__ f3, const ushort16* __restrict__ fcwb,
    const float* __restrict__ fcb, ushort16* __restrict__ feats) {
  int wid = threadIdx.x >> 6, lane = threadIdx.x & 63;
  int l15 = lane & 15, rr = lane >> 4;
  int mt = blockIdx.x * 4 + wid; // 128 M-tiles
  int bn = blockIdx.y;           // 8 groups of 64 channels
  f32x4 ac[4];
#pragma unroll
  for (int t = 0; t < 4; ++t) ac[t] = (f32x4){0.f, 0.f, 0.f, 0.f};
  for (int kb = 0; kb < 98; ++kb) {
    int k0 = kb * 32 + rr * 8;
    short8 af = *(const short8*)(f3 + (mt * 16 + l15) * 3136 + k0);
#pragma unroll
    for (int nt = 0; nt < 4; ++nt) {
      short8 bw = *(const short8*)(fcwb + (bn * 64 + nt * 16 + l15) * 3136 + k0);
      ac[nt] = __builtin_amdgcn_mfma_f32_16x16x32_bf16(af, bw, ac[nt], 0, 0, 0);
    }
  }
#pragma unroll
  for (int nt = 0; nt < 4; ++nt) {
    int ch = bn * 64 + nt * 16 + l15;
    float bia = fcb[ch];
#pragma unroll
    for (int j = 0; j < 4; ++j) {
      int row = mt * 16 + rr * 4 + j;
      feats[row * 512 + ch] = f2bf(relu_(ac[nt][j] + bia));
    }
  }
}

// ---------------- xg: feats @ w_ih^T + b_ih + b_hh -> xgl bf16 in LSTM lane order ----------------
// element (t,b,gate): g=gate>>8, jf=gate&255, w2=jf>>5, q2=(jf>>4)&1, rr=(jf>>2)&3, r=jf&3
// idx = ((((t*16+b)*8 + w2)*2 + q2)*4 + rr)*16 + g*4 + r
__global__ __launch_bounds__(256) void xg_k(
    const ushort16* __restrict__ feats, const ushort16* __restrict__ wihb,
    const float* __restrict__ bih, const float* __restrict__ bhh,
    ushort16* __restrict__ xgl) {
  int wid = threadIdx.x >> 6, lane = threadIdx.x & 63;
  int l15 = lane & 15, rr = lane >> 4;
  int mt = blockIdx.x * 4 + wid; // 128 M-tiles
  int ng = blockIdx.y;           // 16 groups of 64 gates
  f32x4 ac[4];
#pragma unroll
  for (int t = 0; t < 4; ++t) ac[t] = (f32x4){0.f, 0.f, 0.f, 0.f};
#pragma unroll
  for (int kb = 0; kb < 16; ++kb) {
    int k0 = kb * 32 + rr * 8;
    short8 af = *(const short8*)(feats + (mt * 16 + l15) * 512 + k0);
#pragma unroll
    for (int nt = 0; nt < 4; ++nt) {
      short8 bw = *(const short8*)(wihb + (ng * 64 + nt * 16 + l15) * 512 + k0);
      ac[nt] = __builtin_amdgcn_mfma_f32_16x16x32_bf16(af, bw, ac[nt], 0, 0, 0);
    }
  }
#pragma unroll
  for (int nt = 0; nt < 4; ++nt) {
    int gate = ng * 64 + nt * 16 + l15;
    float bia = bih[gate] + bhh[gate];
    int g = gate >> 8, jf = gate & 255;
    int w2 = jf >> 5, q2 = (jf >> 4) & 1, rr2 = (jf >> 2) & 3, r = jf & 3;
#pragma unroll
    for (int j = 0; j < 4; ++j) {
      int row = mt * 16 + rr * 4 + j;
      int tt = row >> 4, bb = row & 15;
      int idx = ((((tt * 16 + bb) * 8 + w2) * 2 + q2) * 4 + rr2) * 16 + g * 4 + r;
      xgl[idx] = f2bf(ac[nt][j] + bia);
    }
  }
}

// ---------------- LSTM scan: 1 block, 8 waves, W_hh fp8 in NAMED registers ----------------
DEV u64 pack8w(const float* p) {
  f32x4 a0 = *(const f32x4*)p;
  f32x4 a1 = *(const f32x4*)(p + 4);
  uint32 lo = pk4_fp8(a0[0], a0[1], a0[2], a0[3]);
  uint32 hi = pk4_fp8(a1[0], a1[1], a1[2], a1[3]);
  return (((u64)hi) << 32) | lo;
}

#define MF(A, B, C) \
  __builtin_amdgcn_mfma_f32_16x16x32_fp8_fp8((long long)(A), (long long)(B), (C), 0, 0, 0)

#define KK8(WA, WB, WC, WD)                                                  \
  a_i = MF(WA##_0, bq0, a_i); a_f = MF(WB##_0, bq0, a_f);                    \
  a_g = MF(WC##_0, bq0, a_g); a_o = MF(WD##_0, bq0, a_o);                    \
  a_i = MF(WA##_1, bq1, a_i); a_f = MF(WB##_1, bq1, a_f);                    \
  a_g = MF(WC##_1, bq1, a_g); a_o = MF(WD##_1, bq1, a_o);                    \
  a_i = MF(WA##_2, bq2, a_i); a_f = MF(WB##_2, bq2, a_f);                    \
  a_g = MF(WC##_2, bq2, a_g); a_o = MF(WD##_2, bq2, a_o);                    \
  a_i = MF(WA##_3, bq3, a_i); a_f = MF(WB##_3, bq3, a_f);                    \
  a_g = MF(WC##_3, bq3, a_g); a_o = MF(WD##_3, bq3, a_o);                    \
  a_i = MF(WA##_4, bq4, a_i); a_f = MF(WB##_4, bq4, a_f);                    \
  a_g = MF(WC##_4, bq4, a_g); a_o = MF(WD##_4, bq4, a_o);                    \
  a_i = MF(WA##_5, bq5, a_i); a_f = MF(WB##_5, bq5, a_f);                    \
  a_g = MF(WC##_5, bq5, a_g); a_o = MF(WD##_5, bq5, a_o);                    \
  a_i = MF(WA##_6, bq6, a_i); a_f = MF(WB##_6, bq6, a_f);                    \
  a_g = MF(WC##_6, bq6, a_g); a_o = MF(WD##_6, bq6, a_o);                    \
  a_i = MF(WA##_7, bq7, a_i); a_f = MF(WB##_7, bq7, a_f);                    \
  a_g = MF(WC##_7, bq7, a_g); a_o = MF(WD##_7, bq7, a_o);

#define XG16(V0, V1, i)                                                      \
  bfh(((i) < 8 ? (uint32)(V0)[((i) >> 1) & 3] : (uint32)(V1)[((i) >> 1) & 3]), \
      ((i) & 1))

#define QSTEP(TT, q2v, WA, WB, WC, WD, XV0, XV1, CV)                         \
  {                                                                          \
    f32x4 a_i = {0.f, 0.f, 0.f, 0.f}, a_f = a_i, a_g = a_i, a_o = a_i;       \
    KK8(WA, WB, WC, WD)                                                      \
    const int j0 = w2 * 32 + (q2v) * 16 + rr * 4;                            \
    f32x4 hv;                                                                \
    _Pragma("unroll") for (int r = 0; r < 4; ++r) {                          \
      float xi = XG16(XV0, XV1, 0 + r);                                      \
      float xf = XG16(XV0, XV1, 4 + r);                                      \
      float xg_ = XG16(XV0, XV1, 8 + r);                                     \
      float xo = XG16(XV0, XV1, 12 + r);                                     \
      float ii = a_i[r] + xi, ff = a_f[r] + xf;                              \
      float gg = a_g[r] + xg_, oo = a_o[r] + xo;                             \
      float cold = CV[r] * mtk;                                              \
      float cn = sigm(ff) * cold + sigm(ii) * tanh_(gg);                     \
      float hn = sigm(oo) * tanh_(cn);                                       \
      CV[r] = cn;                                                            \
      hv[r] = hn;                                                            \
    }                                                                        \
    *(f32x4*)(hs + ((TT) * 16 + b) * 256 + j0) = hv;                         \
    if ((TT) < 127) {                                                        \
      uint32 pk =                                                            \
          pk4_fp8(hv[0] * mnk, hv[1] * mnk, hv[2] * mnk, hv[3] * mnk);       \
      hbw[nxt][((b * 256 + j0) ^ (b << 3)) >> 2] = pk;                       \
    } else {                                                                 \
      *(f32x4*)(out + 12288 + b * 256 + j0) = hv;                            \
      f32x4 cc;                                                              \
      _Pragma("unroll") for (int r = 0; r < 4; ++r) cc[r] = CV[r];           \
      *(f32x4*)(out + 16384 + b * 256 + j0) = cc;                            \
    }                                                                        \
  }

__global__ __launch_bounds__(512, 2) void lstm_k(
    const float* __restrict__ whh, const ushort16* __restrict__ xgl,
    const int* __restrict__ done, const float* __restrict__ h0,
    const float* __restrict__ c0, float* __restrict__ hs,
    float* __restrict__ out) {
  __shared__ uint32 hbw[2][1024]; // h as fp8 [16][256] bytes, XOR-swizzled, dbuf
  int tid = threadIdx.x;
  int w2 = tid >> 6, lane = tid & 63;
  int b = lane & 15, rr = lane >> 4;

  // W_hh fp8 A-fragments in named registers: wg<gq>_<kb>, gq = g*2+q2
#define WD8(gq)                                                              \
  u64 wg##gq##_0, wg##gq##_1, wg##gq##_2, wg##gq##_3, wg##gq##_4,            \
      wg##gq##_5, wg##gq##_6, wg##gq##_7
  WD8(0); WD8(1); WD8(2); WD8(3); WD8(4); WD8(5); WD8(6); WD8(7);
#define LW(gq, g_, q2_)                                                      \
  {                                                                          \
    const float* wp_ =                                                       \
        whh + ((g_) * 256 + w2 * 32 + (q2_) * 16 + b) * 256 + rr * 8;        \
    wg##gq##_0 = pack8w(wp_ + 0);                                            \
    wg##gq##_1 = pack8w(wp_ + 32);                                           \
    wg##gq##_2 = pack8w(wp_ + 64);                                           \
    wg##gq##_3 = pack8w(wp_ + 96);                                           \
    wg##gq##_4 = pack8w(wp_ + 128);                                          \
    wg##gq##_5 = pack8w(wp_ + 160);                                          \
    wg##gq##_6 = pack8w(wp_ + 192);                                          \
    wg##gq##_7 = pack8w(wp_ + 224);                                          \
  }
  LW(0, 0, 0); LW(1, 0, 1); LW(2, 1, 0); LW(3, 1, 1);
  LW(4, 2, 0); LW(5, 2, 1); LW(6, 3, 0); LW(7, 3, 1);

  // c state: 8 per lane in two named f32x4
  f32x4 cv0, cv1;
#pragma unroll
  for (int r = 0; r < 4; ++r) {
    cv0[r] = c0[b * 256 + w2 * 32 + 0 * 16 + rr * 4 + r];
    cv1[r] = c0[b * 256 + w2 * 32 + 1 * 16 + rr * 4 + r];
  }

  // init h buffer 0 = h0 * (1-done[0]) quantized fp8
  {
    int bb = tid >> 5, ck = tid & 31;
    float m0 = 1.f - (float)done[bb];
    const float* hp0 = h0 + bb * 256 + ck * 8;
    uint32 lo = pk4_fp8(hp0[0] * m0, hp0[1] * m0, hp0[2] * m0, hp0[3] * m0);
    uint32 hi = pk4_fp8(hp0[4] * m0, hp0[5] * m0, hp0[6] * m0, hp0[7] * m0);
    u64 v = (((u64)hi) << 32) | lo;
    ((u64*)&hbw[0][0])[((bb * 256 + ck * 8) ^ ((bb & 15) << 3)) >> 3] = v;
  }
  __syncthreads();

  // xg ping-pong register sets (prefetch for t+1 issued BEFORE compute of t)
  u32x4 xvA0, xvA1, xvA2, xvA3;
  u32x4 xvB0, xvB1, xvB2, xvB3;
#define PREF_XG_TO(S, tt)                                                    \
  {                                                                          \
    const ushort16* xp_ = xgl + (((tt) * 16 + b) * 8 + w2) * 128 + rr * 16;  \
    S##0 = *(const u32x4*)(xp_);                                             \
    S##1 = *(const u32x4*)(xp_ + 8);                                         \
    S##2 = *(const u32x4*)(xp_ + 64);                                        \
    S##3 = *(const u32x4*)(xp_ + 72);                                        \
  }
  PREF_XG_TO(xvA, 0);

  u64 bq0, bq1, bq2, bq3, bq4, bq5, bq6, bq7;
#define LB(kb) bq##kb = hp[((b * 256 + (kb) * 32 + rr * 8) ^ (b << 3)) >> 3]

#define STEP(TT, XC, XN)                                                     \
  {                                                                          \
    const int t_ = (TT);                                                     \
    const int cur = t_ & 1, nxt = cur ^ 1;                                   \
    const u64* hp = (const u64*)&hbw[cur][0];                                \
    LB(0); LB(1); LB(2); LB(3); LB(4); LB(5); LB(6); LB(7);                  \
    float mtk = 1.f - (float)done[t_ * 16 + b];                              \
    float mnk = (t_ < 127) ? (1.f - (float)done[(t_ + 1) * 16 + b]) : 0.f;   \
    {                                                                        \
      int tn_ = t_ < 127 ? t_ + 1 : 127;                                     \
      PREF_XG_TO(XN, tn_);                                                   \
    }                                                                        \
    QSTEP(t_, 0, wg0, wg2, wg4, wg6, XC##0, XC##1, cv0)                      \
    QSTEP(t_, 1, wg1, wg3, wg5, wg7, XC##2, XC##3, cv1)                      \
    __syncthreads();                                                         \
  }

  for (int th = 0; th < 64; ++th) {
    STEP(2 * th, xvA, xvB);
    STEP(2 * th + 1, xvB, xvA);
  }
}

// ---------------- heads: logits = hs@pol_w^T+pb ; v = hs@val_w^T+vb ----------------
__global__ __launch_bounds__(256) void heads_k(
    const float* __restrict__ hs, const float* __restrict__ pw,
    const float* __restrict__ pb, const float* __restrict__ vw,
    const float* __restrict__ vb, float* __restrict__ out) {
  __shared__ float wsm[1536];
  int tid = threadIdx.x;
  for (int i = tid; i < 1536; i += 256) wsm[i] = (i < 1280) ? pw[i] : vw[i - 1280];
  __syncthreads();
  int r = blockIdx.x * 256 + tid;
  const f32x4* hp = (const f32x4*)(hs + r * 256);
  float a[6] = {0.f, 0.f, 0.f, 0.f, 0.f, 0.f};
  for (int j = 0; j < 64; ++j) {
    f32x4 h = hp[j];
#pragma unroll
    for (int w = 0; w < 6; ++w) {
      f32x4 wv = *(const f32x4*)(wsm + w * 256 + j * 4);
      a[w] += h[0] * wv[0] + h[1] * wv[1] + h[2] * wv[2] + h[3] * wv[3];
    }
  }
#pragma unroll
  for (int w = 0; w < 5; ++w) out[r * 5 + w] = a[w] + pb[w];
  out[10240 + r] = a[5] + vb[0];
}

// ---------------- launch ----------------
extern "C" void kernel_launch(void* const* d_in, const int* in_sizes, int n_in,
                              void* d_out, int out_size, void* d_ws,
                              size_t ws_size, hipStream_t stream) {
  const float* img = (const float*)d_in[0];
  const int* done = (const int*)d_in[1];
  const float* h0 = (const float*)d_in[2];
  const float* c0 = (const float*)d_in[3];
  const float* c1w = (const float*)d_in[4];
  const float* c1b = (const float*)d_in[5];
  const float* c2w = (const float*)d_in[6];
  const float* c2b = (const float*)d_in[7];
  const float* c3w = (const float*)d_in[8];
  const float* c3b = (const float*)d_in[9];
  const float* fcw = (const float*)d_in[10];
  const float* fcb = (const float*)d_in[11];
  const float* wih = (const float*)d_in[12];
  const float* whh = (const float*)d_in[13];
  const float* bih = (const float*)d_in[14];
  const float* bhh = (const float*)d_in[15];
  const float* pw = (const float*)d_in[16];
  const float* pb = (const float*)d_in[17];
  const float* vw = (const float*)d_in[18];
  const float* vb = (const float*)d_in[19];
  float* out = (float*)d_out;
  char* ws = (char*)d_ws;

  ushort16* w1b = (ushort16*)(ws + 0);          //    16384
  ushort16* w2r = (ushort16*)(ws + 16384);      //    65536
  ushort16* w3r = (ushort16*)(ws + 81920);      //    73728
  ushort16* fcwb = (ushort16*)(ws + 155648);    //  3211264
  ushort16* wihb = (ushort16*)(ws + 3366912);   //  1048576
  ushort16* out1 = (ushort16*)(ws + 4415488);   // 52428800
  ushort16* out2 = (ushort16*)(ws + 56844288);  // 21233664
  ushort16* f3 = (ushort16*)(ws + 78077952);    // 12845056
  ushort16* feats = (ushort16*)(ws + 90923008); //  2097152
  ushort16* xgl = (ushort16*)(ws + 93020160);   //  4194304
  float* hs = (float*)(ws + 97214464);          //  2097152

  prep_k<<<8624, 256, 0, stream>>>(c1w, c2w, c3w, fcw, wih, w1b, w2r, w3r, fcwb, wihb);
  conv1_k<<<12800, 256, 0, stream>>>(img, w1b, c1b, out1);
  conv2_k<<<2592, 256, 0, stream>>>(out1, w2r, c2b, out2);
  conv3_k<<<1568, 256, 0, stream>>>(out2, w3r, c3b, f3);
  fc_k<<<dim3(32, 8), 256, 0, stream>>>(f3, fcwb, fcb, feats);
  xg_k<<<dim3(32, 16), 256, 0, stream>>>(feats, wihb, bih, bhh, xgl);
  lstm_k<<<1, 512, 0, stream>>>(whh, xgl, done, h0, c0, hs, out);
  heads_k<<<8, 256, 0, stream>>>(hs, pw, pb, vw, vb, out);
}